// Round 6
// baseline (753.322 us; speedup 1.0000x reference)
//
#include <hip/hip_runtime.h>
#include <stdint.h>

#define T_DIM 512
#define B_DIM 64
#define D_DIM 1024
#define H_DIM 8
#define DH_DIM 128
#define MROWS (T_DIM * B_DIM)   // 32768 rows across all timesteps

typedef unsigned short u16;
typedef __attribute__((ext_vector_type(8))) __bf16 bf16x8;
typedef __attribute__((ext_vector_type(4))) float f32x4;
typedef __attribute__((ext_vector_type(16))) float f32x16;

__device__ __forceinline__ u16 f2bf(float f) {
  union { float f; uint32_t u; } v; v.f = f;
  uint32_t u = v.u;
  u += 0x7fffu + ((u >> 16) & 1u);   // RNE
  return (u16)(u >> 16);
}
__device__ __forceinline__ float bf2f(u16 h) {
  union { uint32_t u; float f; } v; v.u = ((uint32_t)h) << 16;
  return v.f;
}

__device__ __forceinline__ void gload16(const void* g, void* l) {
  __builtin_amdgcn_global_load_lds(
      (const __attribute__((address_space(1))) uint32_t*)g,
      (__attribute__((address_space(3))) uint32_t*)l, 16, 0, 0);
}

#define SB()  __builtin_amdgcn_sched_barrier(0)
#define BAR() __builtin_amdgcn_s_barrier()
#define VM4() asm volatile("s_waitcnt vmcnt(4)" ::: "memory")

// ---------------- elementwise prep ----------------

__global__ void cast_bf16_kernel(const float* __restrict__ in, u16* __restrict__ out, size_t n8) {
  size_t i = (size_t)blockIdx.x * blockDim.x + threadIdx.x;
  const size_t stride = (size_t)gridDim.x * blockDim.x;
  for (; i < n8; i += stride) {
    const float4 a = ((const float4*)in)[i * 2];
    const float4 b = ((const float4*)in)[i * 2 + 1];
    union { u16 h[8]; uint4 u; } o;
    o.h[0] = f2bf(a.x); o.h[1] = f2bf(a.y); o.h[2] = f2bf(a.z); o.h[3] = f2bf(a.w);
    o.h[4] = f2bf(b.x); o.h[5] = f2bf(b.y); o.h[6] = f2bf(b.z); o.h[7] = f2bf(b.w);
    ((uint4*)out)[i] = o.u;
  }
}

// Wc[n][k] = Wr[n][k]+Wi[n][k] (k<1024)  |  Wr[n][k-1024]-Wi[n][k-1024]  -> (1024, 2048) bf16
__global__ void prep_wc_kernel(const float* __restrict__ Wr, const float* __restrict__ Wi,
                               u16* __restrict__ Wc) {
  const int idx = blockIdx.x * 256 + threadIdx.x;  // over 1024*2048
  const int n = idx >> 11;
  const int k = idx & 2047;
  const int kk = k & 1023;
  const float a = Wr[n * 1024 + kk], b = Wi[n * 1024 + kk];
  Wc[idx] = f2bf(k < 1024 ? a + b : a - b);
}

__global__ void prep_bc_kernel(const float* __restrict__ br, const float* __restrict__ bi,
                               float* __restrict__ bc) {
  const int i = blockIdx.x * 256 + threadIdx.x;
  if (i < D_DIM) bc[i] = br[i] + bi[i];
}

// ---------------- 256x256 8-phase bf16 MFMA GEMM (32x32x16), register-ping-pong ----------------
// 512 threads = 8 waves (2M x 4N), per-wave C 128x64 = 4x2 frags of 32x32, BK=64, 2 K-tiles/iter.
// LDS 128 KB: [buf:2][ Ak0 | Ak1 | Bk0 | Bk1 ], half-tile 8192 u16 = 16 KB ([row][4 punits][8]).
// Swizzle: punit stored = u ^ (r&3) ^ ((r>>2)&3) via inverse-swizzled GLOBAL source (rule #21);
// read punit lane-constant; verified 0 bank conflicts (round 5 PMC).
// Pipelining: A-fragments for phase p+1 are pre-read during phase p (sets a0/a1 ping-pong);
// at buffer-boundary phases (ph0, ph4) A+B self-read (their half-tile residency is only
// cross-wave-guaranteed after the preceding vmcnt+barrier). B single set (VGPR budget),
// self-read at each QM0 phase, reused by the QM1 phase.
// Stage rotation per iter (tiles u=2i buf0, v=2i+1 buf1), UNchanged from round 4/5:
//   ph0:Ak1(v)->b1  ph1:Bk1(v)->b1  ph2:Ak0(u+2)->b0  ph3:Bk0(u+2)->b0
//   ph4:Ak1(u+2)->b0 ph5:Bk1(u+2)->b0 ph6:Ak0(v+2)->b1 ph7:Bk0(v+2)->b1
// vmcnt(4) ONLY at ph3/ph7 end (counted wait, never 0 in loop).

__device__ __forceinline__ void readF(bf16x8 (&d)[2][2], const u16* s, int rowoff, int la32, int puA) {
#pragma unroll
  for (int mf = 0; mf < 2; ++mf)
#pragma unroll
    for (int kk = 0; kk < 2; ++kk)
      d[mf][kk] = *(const bf16x8*)(s + (rowoff + mf * 32 + la32) * 32 + (puA ^ (kk << 4)));
}

__device__ __forceinline__ void mfma8(f32x16 (&acc)[4][2], const bf16x8 (&a)[2][2],
                                      const bf16x8 (&b)[2][2], int QM) {
#pragma unroll
  for (int kk = 0; kk < 2; ++kk)
#pragma unroll
    for (int mf = 0; mf < 2; ++mf)
#pragma unroll
      for (int nf = 0; nf < 2; ++nf)
        acc[QM * 2 + mf][nf] =
            __builtin_amdgcn_mfma_f32_32x32x16_bf16(a[mf][kk], b[nf][kk], acc[QM * 2 + mf][nf], 0, 0, 0);
}

template <int EPI>
__global__ __launch_bounds__(512, 2) void gemm256_kernel(
    const u16* __restrict__ A0, const u16* __restrict__ A1, int kSplit, int lda,
    const u16* __restrict__ Bw, int ldb,
    const float* __restrict__ bias,
    void* __restrict__ C0, void* __restrict__ C1, void* __restrict__ C2,
    int ldc, int K, int nColBlk)
{
  extern __shared__ u16 lds[];   // 65536 u16 = 128 KB
  const int tid  = threadIdx.x;
  const int lane = tid & 63;
  const int w    = tid >> 6;
  const int wr   = w >> 2;       // 0..1
  const int wc   = w & 3;        // 0..3

  // XCD-contiguous swizzle: bid%8 -> XCD, 16 row-panels per XCD, row-major within band
  const int bid   = blockIdx.x;
  const int xcd   = bid & 7;
  const int local = bid >> 3;
  const int rowL  = local / nColBlk;
  const int colB  = local - rowL * nColBlk;
  const size_t rowBase = (size_t)(xcd * 16 + rowL) * 256;
  const size_t colBase = (size_t)colB * 256;

  f32x16 acc[4][2];
#pragma unroll
  for (int i = 0; i < 4; ++i)
#pragma unroll
    for (int j = 0; j < 2; ++j)
#pragma unroll
      for (int e = 0; e < 16; ++e) acc[i][j][e] = 0.f;

  const int NT = K >> 6;
  const int la32 = lane & 31;
  const int g2   = lane >> 5;
  const int f    = (la32 & 3) ^ ((la32 >> 2) & 3);
  const int puA  = ((g2 ^ f) << 3);   // u16 units; kk=1 -> ^16

  // stage one half-tile (2 gload16/thread), linear LDS dest + inverse-swizzled global source
  auto stageA = [&](int buf, int ks, int t) {
    if (t >= NT) return;
    const int kb = t * 64;
    const u16* Ab; int kc;
    if (kb < kSplit) { Ab = A0; kc = kb; } else { Ab = A1; kc = kb - kSplit; }
    u16* dst = lds + buf * 32768 + ks * 8192;
#pragma unroll
    for (int i2 = 0; i2 < 2; ++i2) {
      const int l = i2 * 512 + tid, r = l >> 2, p = l & 3;
      const int lu = p ^ (r & 3) ^ ((r >> 2) & 3);
      gload16(Ab + (rowBase + r) * (size_t)lda + kc + ks * 32 + lu * 8, dst + l * 8);
    }
  };
  auto stageB = [&](int buf, int ks, int t) {
    if (t >= NT) return;
    const int kb = t * 64;
    u16* dst = lds + buf * 32768 + 16384 + ks * 8192;
#pragma unroll
    for (int i2 = 0; i2 < 2; ++i2) {
      const int l = i2 * 512 + tid, r = l >> 2, p = l & 3;
      const int lu = p ^ (r & 3) ^ ((r >> 2) & 3);
      gload16(Bw + (colBase + r) * (size_t)ldb + kb + ks * 32 + lu * 8, dst + l * 8);
    }
  };

  // LDS half-tile bases
  const u16* sA_b0k0 = lds;
  const u16* sA_b0k1 = lds + 8192;
  const u16* sB_b0k0 = lds + 16384;
  const u16* sB_b0k1 = lds + 16384 + 8192;
  const u16* sA_b1k0 = lds + 32768;
  const u16* sA_b1k1 = lds + 32768 + 8192;
  const u16* sB_b1k0 = lds + 32768 + 16384;
  const u16* sB_b1k1 = lds + 32768 + 16384 + 8192;
  const int rA0 = wr * 128;        // QM0 A rows
  const int rA1 = wr * 128 + 64;   // QM1 A rows
  const int rB  = wc * 64;

  // prologue: tile0 complete + tile1 k0-halves  (12 loads in flight)
  stageA(0, 0, 0); stageB(0, 0, 0); stageA(0, 1, 0); stageB(0, 1, 0);
  stageA(1, 0, 1); stageB(1, 0, 1);
  VM4();   // tile0 resident; tile1.k0 may fly
  SB(); BAR(); SB();

  bf16x8 a0[2][2], a1[2][2], bb[2][2];
  const int NIT = NT >> 1;
  for (int i = 0; i < NIT; ++i) {
    const int u = 2 * i, v = 2 * i + 1;
    // ph0 (b0k0,QM0): self a0+bb, pre a1 (ph1, same region)
    readF(a0, sA_b0k0, rA0, la32, puA);
    readF(bb, sB_b0k0, rB,  la32, puA);
    readF(a1, sA_b0k0, rA1, la32, puA);
    stageA(1, 1, v);
    SB(); BAR(); SB();
    __builtin_amdgcn_s_setprio(1); mfma8(acc, a0, bb, 0); __builtin_amdgcn_s_setprio(0); SB();
    BAR(); SB();
    // ph1 (b0k0,QM1): pre a0 <- ph2 (b0k1,QM0)
    readF(a0, sA_b0k1, rA0, la32, puA);
    stageB(1, 1, v);
    SB(); BAR(); SB();
    __builtin_amdgcn_s_setprio(1); mfma8(acc, a1, bb, 1); __builtin_amdgcn_s_setprio(0); SB();
    BAR(); SB();
    // ph2 (b0k1,QM0): self bb(b0k1), pre a1 <- ph3
    readF(bb, sB_b0k1, rB,  la32, puA);
    readF(a1, sA_b0k1, rA1, la32, puA);
    stageA(0, 0, u + 2);
    SB(); BAR(); SB();
    __builtin_amdgcn_s_setprio(1); mfma8(acc, a0, bb, 0); __builtin_amdgcn_s_setprio(0); SB();
    BAR(); SB();
    // ph3 (b0k1,QM1): no reads
    stageB(0, 0, u + 2);
    SB(); BAR(); SB();
    __builtin_amdgcn_s_setprio(1); mfma8(acc, a1, bb, 1); __builtin_amdgcn_s_setprio(0); SB();
    VM4(); BAR(); SB();
    // ph4 (b1k0,QM0): self a0+bb, pre a1
    readF(a0, sA_b1k0, rA0, la32, puA);
    readF(bb, sB_b1k0, rB,  la32, puA);
    readF(a1, sA_b1k0, rA1, la32, puA);
    stageA(0, 1, u + 2);
    SB(); BAR(); SB();
    __builtin_amdgcn_s_setprio(1); mfma8(acc, a0, bb, 0); __builtin_amdgcn_s_setprio(0); SB();
    BAR(); SB();
    // ph5 (b1k0,QM1): pre a0 <- ph6 (b1k1,QM0)
    readF(a0, sA_b1k1, rA0, la32, puA);
    stageB(0, 1, u + 2);
    SB(); BAR(); SB();
    __builtin_amdgcn_s_setprio(1); mfma8(acc, a1, bb, 1); __builtin_amdgcn_s_setprio(0); SB();
    BAR(); SB();
    // ph6 (b1k1,QM0): self bb(b1k1), pre a1 <- ph7
    readF(bb, sB_b1k1, rB,  la32, puA);
    readF(a1, sA_b1k1, rA1, la32, puA);
    stageA(1, 0, v + 2);
    SB(); BAR(); SB();
    __builtin_amdgcn_s_setprio(1); mfma8(acc, a0, bb, 0); __builtin_amdgcn_s_setprio(0); SB();
    BAR(); SB();
    // ph7 (b1k1,QM1): no reads
    stageB(1, 0, v + 2);
    SB(); BAR(); SB();
    __builtin_amdgcn_s_setprio(1); mfma8(acc, a1, bb, 1); __builtin_amdgcn_s_setprio(0); SB();
    VM4(); BAR(); SB();
  }

  // epilogue: segment-select output buffer (colBase multiple of 256 -> block-uniform segment)
  const int seg = (int)(colBase >> 10);
  const size_t colSeg = colBase & 1023;
  void* Cout;
  if (EPI == 3)      Cout = (seg == 0) ? C0 : (seg == 1) ? C1 : C2;
  else if (EPI == 2) Cout = (seg == 0) ? C0 : C1;
  else               Cout = C0;

  // C/D layout (32x32x16, m74/m101): col = lane&31, row = (r&3) + 8*(r>>2) + 4*(lane>>5)
#pragma unroll
  for (int mi = 0; mi < 4; ++mi)
#pragma unroll
    for (int ni = 0; ni < 2; ++ni) {
      const int cn = wc * 64 + ni * 32 + la32;
      const float badd = (EPI == 1) ? bias[colBase + cn] : 0.0f;
      const size_t col = colSeg + cn;
#pragma unroll
      for (int r = 0; r < 16; ++r) {
        const size_t row = rowBase + wr * 128 + mi * 32 + (r & 3) + 8 * (r >> 2) + 4 * g2;
        const float v = acc[mi][ni][r] + badd;
        if (EPI == 2) ((float*)Cout)[row * (size_t)ldc + col] = v;
        else          ((u16*)Cout)[row * (size_t)ldc + col] = f2bf(v);
      }
    }
}

// ---------------- LayerNorm (in-place on bf16 rows) ----------------

__global__ __launch_bounds__(256) void ln_kernel(u16* __restrict__ xc,
    const float* __restrict__ gamma, const float* __restrict__ beta)
{
  const size_t row = blockIdx.x;
  u16* p = xc + row * D_DIM;
  const int tid = threadIdx.x;
  const int c = tid * 4;
  const uint2 raw = *(const uint2*)(p + c);
  const float v0 = bf2f((u16)(raw.x & 0xffff)), v1 = bf2f((u16)(raw.x >> 16));
  const float v2 = bf2f((u16)(raw.y & 0xffff)), v3 = bf2f((u16)(raw.y >> 16));
  float s = v0 + v1 + v2 + v3;
  float q = v0 * v0 + v1 * v1 + v2 * v2 + v3 * v3;
#pragma unroll
  for (int o = 32; o > 0; o >>= 1) { s += __shfl_xor(s, o); q += __shfl_xor(q, o); }
  __shared__ float red[8];
  if ((tid & 63) == 0) { red[(tid >> 6) * 2] = s; red[(tid >> 6) * 2 + 1] = q; }
  __syncthreads();
  s = red[0] + red[2] + red[4] + red[6];
  q = red[1] + red[3] + red[5] + red[7];
  const float mu = s * (1.0f / D_DIM);
  const float var = q * (1.0f / D_DIM) - mu * mu;
  const float rstd = 1.0f / sqrtf(var + 1e-5f);
  const float y0 = (v0 - mu) * rstd * gamma[c] + beta[c];
  const float y1 = (v1 - mu) * rstd * gamma[c + 1] + beta[c + 1];
  const float y2 = (v2 - mu) * rstd * gamma[c + 2] + beta[c + 2];
  const float y3 = (v3 - mu) * rstd * gamma[c + 3] + beta[c + 3];
  const uint32_t o0 = (uint32_t)f2bf(y0) | ((uint32_t)f2bf(y1) << 16);
  const uint32_t o1 = (uint32_t)f2bf(y2) | ((uint32_t)f2bf(y3) << 16);
  *(uint2*)(p + c) = make_uint2(o0, o1);
}

// ---------------- gate[row,h] = sigmoid(q.k / sqrt(DH)) — one wave per (row,h) ----------------

__global__ __launch_bounds__(256) void gate_kernel(
    const u16* __restrict__ Q, const u16* __restrict__ Kb, float* __restrict__ gate)
{
  const int gw = blockIdx.x * 4 + (threadIdx.x >> 6);   // wave id: row*8 + h
  const int lane = threadIdx.x & 63;
  const size_t row = (size_t)(gw >> 3);
  const int h = gw & 7;
  const size_t off = row * D_DIM + h * DH_DIM + lane * 2;
  const uint32_t qr = *(const uint32_t*)(Q + off);
  const uint32_t kr = *(const uint32_t*)(Kb + off);
  float d = bf2f((u16)(qr & 0xffff)) * bf2f((u16)(kr & 0xffff))
          + bf2f((u16)(qr >> 16))    * bf2f((u16)(kr >> 16));
#pragma unroll
  for (int o = 32; o > 0; o >>= 1) d += __shfl_xor(d, o);
  if (lane == 0) {
    const float x = d * 0.08838834764831845f;  // 1/sqrt(128)
    gate[gw] = 1.0f / (1.0f + expf(-x));
  }
}

// ---------------- sequential EMA scan over T (parallel over B*D) ----------------

__global__ __launch_bounds__(256) void scan_kernel(
    const u16* __restrict__ vb, const float* __restrict__ gate,
    const float* __restrict__ vstate, const float* __restrict__ log_alpha,
    u16* __restrict__ ret, float* __restrict__ fstate)
{
  const int gid = blockIdx.x * 256 + threadIdx.x;   // b*1024 + h*128 + d
  const int b = gid >> 10;
  const int c = gid & 1023;
  const int h = c >> 7;
  const float alpha = 1.0f / (1.0f + expf(-log_alpha[h]));
  const float oma = 1.0f - alpha;
  float state = vstate[gid];
  const u16* vp = vb + (size_t)b * D_DIM + c;
  u16* rp = ret + (size_t)b * D_DIM + c;
  const float* gp = gate + b * H_DIM + h;
#pragma unroll 4
  for (int t = 0; t < T_DIM; ++t) {
    const float v = bf2f(vp[(size_t)t * (B_DIM * D_DIM)]);
    const float g = gp[(size_t)t * (B_DIM * H_DIM)];
    state = alpha * v + oma * state;
    rp[(size_t)t * (B_DIM * D_DIM)] = f2bf(g * state);
  }
  fstate[gid] = state;
}

// ---------------- launch ----------------

extern "C" void kernel_launch(void* const* d_in, const int* in_sizes, int n_in,
                              void* d_out, int out_size, void* d_ws, size_t ws_size,
                              hipStream_t stream) {
  const float* x_real      = (const float*)d_in[0];
  const float* x_imag      = (const float*)d_in[1];
  const float* value_state = (const float*)d_in[2];
  // d_in[3] = t (unused by the math)
  const float* Wr_in  = (const float*)d_in[4];
  const float* Wi_in  = (const float*)d_in[5];
  const float* br_in  = (const float*)d_in[6];
  const float* bi_in  = (const float*)d_in[7];
  const float* ln_g   = (const float*)d_in[8];
  const float* ln_b   = (const float*)d_in[9];
  const float* W_qkv  = (const float*)d_in[10];
  const float* log_alpha = (const float*)d_in[11];
  const float* Wr_out = (const float*)d_in[12];
  const float* Wi_out = (const float*)d_in[13];

  float* out_real = (float*)d_out;
  float* out_imag = out_real + (size_t)MROWS * D_DIM;
  float* fstate   = out_imag + (size_t)MROWS * D_DIM;

  // Scratch carved out of d_out (regions dead until the final out-proj GEMM):
  u16* R0a = (u16*)d_out;                                        // xr -> Q -> (dead)
  u16* xc  = (u16*)((char*)d_out + (size_t)MROWS * D_DIM * 2);   // proj out, LN'd
  u16* Vb  = (u16*)out_imag;                                     // V

  // d_ws buffers (~79 MB)
  char* ws = (char*)d_ws;
  size_t off = 0;
  auto alloc = [&](size_t bytes) { void* p = ws + off; off += (bytes + 255) & ~(size_t)255; return p; };
  u16*   Wc    = (u16*)alloc((size_t)1024 * 2048 * 2);
  u16*   Wqkvb = (u16*)alloc((size_t)3072 * 1024 * 2);
  u16*   Wob   = (u16*)alloc((size_t)2048 * 1024 * 2);   // [Wr_out; Wi_out]
  float* bc    = (float*)alloc((size_t)D_DIM * 4);
  u16*   R0b   = (u16*)alloc((size_t)MROWS * D_DIM * 2); // xi -> K -> retrieved
  float* gate  = (float*)alloc((size_t)MROWS * H_DIM * 4);

  // allow 128 KB dynamic LDS for the GEMM instantiations (host-side, capture-safe)
  const int LDSB = 131072;
  hipFuncSetAttribute((const void*)gemm256_kernel<1>, hipFuncAttributeMaxDynamicSharedMemorySize, LDSB);
  hipFuncSetAttribute((const void*)gemm256_kernel<2>, hipFuncAttributeMaxDynamicSharedMemorySize, LDSB);
  hipFuncSetAttribute((const void*)gemm256_kernel<3>, hipFuncAttributeMaxDynamicSharedMemorySize, LDSB);

  // --- weight prep ---
  prep_wc_kernel<<<(1024 * 2048) / 256, 256, 0, stream>>>(Wr_in, Wi_in, Wc);
  prep_bc_kernel<<<4, 256, 0, stream>>>(br_in, bi_in, bc);
  cast_bf16_kernel<<<1536, 256, 0, stream>>>(W_qkv, Wqkvb, (size_t)3072 * 1024 / 8);
  cast_bf16_kernel<<<512, 256, 0, stream>>>(Wr_out, Wob, (size_t)1024 * 1024 / 8);
  cast_bf16_kernel<<<512, 256, 0, stream>>>(Wi_out, Wob + (size_t)1024 * 1024, (size_t)1024 * 1024 / 8);
  // --- activation casts ---
  cast_bf16_kernel<<<4096, 256, 0, stream>>>(x_real, R0a, (size_t)MROWS * D_DIM / 8);
  cast_bf16_kernel<<<4096, 256, 0, stream>>>(x_imag, R0b, (size_t)MROWS * D_DIM / 8);

  // input proj: xc_pre = [xr|xi] @ Wc^T + bc   (K=2048, split at 1024) -> xc
  gemm256_kernel<1><<<dim3(128 * 4), 512, LDSB, stream>>>(
      R0a, R0b, 1024, 1024, Wc, 2048, bc, xc, nullptr, nullptr, 1024, 2048, 4);
  // LayerNorm in place
  ln_kernel<<<MROWS, 256, 0, stream>>>(xc, ln_g, ln_b);
  // QKV in ONE GEMM (N=3072): Q -> R0a, K -> R0b, V -> Vb
  gemm256_kernel<3><<<dim3(128 * 12), 512, LDSB, stream>>>(
      xc, xc, 1024, 1024, Wqkvb, 1024, nullptr, R0a, R0b, Vb, 1024, 1024, 12);
  // gate from Q,K
  gate_kernel<<<(MROWS * H_DIM) / 4, 256, 0, stream>>>(R0a, R0b, gate);
  // EMA scan: retrieved -> R0b (overwrites dead K), final_state -> d_out tail
  scan_kernel<<<(B_DIM * D_DIM) / 256, 256, 0, stream>>>(Vb, gate, value_state, log_alpha, R0b, fstate);
  // output projections in ONE GEMM (N=2048, f32 out): -> out_real | out_imag
  gemm256_kernel<2><<<dim3(128 * 8), 512, LDSB, stream>>>(
      R0b, R0b, 1024, 1024, Wob, 1024, nullptr, out_real, out_imag, nullptr, 1024, 1024, 8);
}

// Round 8
// 750.777 us; speedup vs baseline: 1.0034x; 1.0034x over previous
//
#include <hip/hip_runtime.h>
#include <stdint.h>

#define T_DIM 512
#define B_DIM 64
#define D_DIM 1024
#define H_DIM 8
#define DH_DIM 128
#define MROWS (T_DIM * B_DIM)   // 32768 rows across all timesteps

typedef unsigned short u16;
typedef __attribute__((ext_vector_type(8))) __bf16 bf16x8;
typedef __attribute__((ext_vector_type(4))) float f32x4;
typedef __attribute__((ext_vector_type(16))) float f32x16;

__device__ __forceinline__ u16 f2bf(float f) {
  union { float f; uint32_t u; } v; v.f = f;
  uint32_t u = v.u;
  u += 0x7fffu + ((u >> 16) & 1u);   // RNE
  return (u16)(u >> 16);
}
__device__ __forceinline__ float bf2f(u16 h) {
  union { uint32_t u; float f; } v; v.u = ((uint32_t)h) << 16;
  return v.f;
}

__device__ __forceinline__ void gload16(const void* g, void* l) {
  __builtin_amdgcn_global_load_lds(
      (const __attribute__((address_space(1))) uint32_t*)g,
      (__attribute__((address_space(3))) uint32_t*)l, 16, 0, 0);
}

#define SB()  __builtin_amdgcn_sched_barrier(0)
#define BAR() __builtin_amdgcn_s_barrier()
#define VM4() asm volatile("s_waitcnt vmcnt(4)" ::: "memory")
#define VM6() asm volatile("s_waitcnt vmcnt(6)" ::: "memory")
#define PRIO1() __builtin_amdgcn_s_setprio(1)
#define PRIO0() __builtin_amdgcn_s_setprio(0)

// ---------------- elementwise prep ----------------

__global__ void cast_bf16_kernel(const float* __restrict__ in, u16* __restrict__ out, size_t n8) {
  size_t i = (size_t)blockIdx.x * blockDim.x + threadIdx.x;
  const size_t stride = (size_t)gridDim.x * blockDim.x;
  for (; i < n8; i += stride) {
    const float4 a = ((const float4*)in)[i * 2];
    const float4 b = ((const float4*)in)[i * 2 + 1];
    union { u16 h[8]; uint4 u; } o;
    o.h[0] = f2bf(a.x); o.h[1] = f2bf(a.y); o.h[2] = f2bf(a.z); o.h[3] = f2bf(a.w);
    o.h[4] = f2bf(b.x); o.h[5] = f2bf(b.y); o.h[6] = f2bf(b.z); o.h[7] = f2bf(b.w);
    ((uint4*)out)[i] = o.u;
  }
}

// Wc[n][k] = Wr[n][k]+Wi[n][k] (k<1024)  |  Wr[n][k-1024]-Wi[n][k-1024]  -> (1024, 2048) bf16
__global__ void prep_wc_kernel(const float* __restrict__ Wr, const float* __restrict__ Wi,
                               u16* __restrict__ Wc) {
  const int idx = blockIdx.x * 256 + threadIdx.x;  // over 1024*2048
  const int n = idx >> 11;
  const int k = idx & 2047;
  const int kk = k & 1023;
  const float a = Wr[n * 1024 + kk], b = Wi[n * 1024 + kk];
  Wc[idx] = f2bf(k < 1024 ? a + b : a - b);
}

__global__ void prep_bc_kernel(const float* __restrict__ br, const float* __restrict__ bi,
                               float* __restrict__ bc) {
  const int i = blockIdx.x * 256 + threadIdx.x;
  if (i < D_DIM) bc[i] = br[i] + bi[i];
}

// ------- 256x256 8-phase bf16 MFMA GEMM (32x32x16), one-phase-ahead register pipeline -------
// 512 threads = 8 waves (2M x 4N), per-wave C 128x64 = 4x2 frags of 32x32, BK=64, 2 K-tiles/iter.
// LDS 128 KB: [buf:2][ Ak0 | Ak1 | Bk0 | Bk1 ], half-tile 8192 u16 = 16 KB ([row][4 punits][8]).
// Swizzle: punit stored = u ^ (r&3) ^ ((r>>2)&3) via inverse-swizzled GLOBAL source (rule #21);
// read punit lane-constant; 0 bank conflicts (round-5 PMC).
// NO manual lgkmcnt drains: reads for phase p+1 issue in phase p; compiler inserts
// dependency-exact counted lgkmcnt before each MFMA, so pre-reads complete under p's MFMA.
// A ping-pong (a0/a1) + B ping-pong (bbE/bbO).
// Reads by phase: ph0 self a0,bbE + pre a1 (b0k0); ph1 a0,bbO (b0k1); ph2 a1 (b0k1);
//   ph3 a0,bbE (b1k0); ph4 a1 (b1k0); ph5 a0,bbO (b1k1); ph6 a1 (b1k1); ph7 none.
// Stage rotation (tiles u=2i buf0, v=2i+1 buf1):
//   ph0:Ak1(v)->b1  ph1:Bk1(v)->b1  ph2:Ak0(u+2)->b0  ph3:Bk0(u+2)->b0
//   ph4:Ak1(u+2)->b0 ph5:Bk1(u+2)->b0 ph6:Ak0(v+2)->b1 ph7:Bk0(v+2)->b1
// Counted vmcnt (all BEFORE a barrier -> cross-wave safe):
//   ph2-end vmcnt(6): drains prev ph6/ph7 stages -> b1k0 resident for ph3/ph4 reads
//   ph3-end vmcnt(4): drains ph0/ph1 stages     -> b1k1 resident for ph5/ph6 reads
//   ph7-end vmcnt(4): drains ph2..ph5 stages    -> buf0 tile u+2 complete for next ph0-ph2
// Queue arithmetic: 10->6, 8->4, 12->4 each iter; never drained to 0 in the loop.
// ROUND-7 RACE FIX: tail iterations must NOT skip stages (skipping breaks the counted-vmcnt
// queue arithmetic -> vmcnt(6)/(4) no longer cover the half-tile being read -> stale reads on
// the final K-tile pair, absmax 0.80). Out-of-range tiles CLAMP to t=0: dummy stages into
// regions provably never read after the last iteration, keeping the queue exact.

__device__ __forceinline__ void readF(bf16x8 (&d)[2][2], const u16* s, int rowoff, int la32, int puA) {
#pragma unroll
  for (int mf = 0; mf < 2; ++mf)
#pragma unroll
    for (int kk = 0; kk < 2; ++kk)
      d[mf][kk] = *(const bf16x8*)(s + (rowoff + mf * 32 + la32) * 32 + (puA ^ (kk << 4)));
}

__device__ __forceinline__ void mfma8(f32x16 (&acc)[4][2], const bf16x8 (&a)[2][2],
                                      const bf16x8 (&b)[2][2], int QM) {
#pragma unroll
  for (int kk = 0; kk < 2; ++kk)
#pragma unroll
    for (int mf = 0; mf < 2; ++mf)
#pragma unroll
      for (int nf = 0; nf < 2; ++nf)
        acc[QM * 2 + mf][nf] =
            __builtin_amdgcn_mfma_f32_32x32x16_bf16(a[mf][kk], b[nf][kk], acc[QM * 2 + mf][nf], 0, 0, 0);
}

template <int EPI>
__global__ __launch_bounds__(512, 2) void gemm256_kernel(
    const u16* __restrict__ A0, const u16* __restrict__ A1, int kSplit, int lda,
    const u16* __restrict__ Bw, int ldb,
    const float* __restrict__ bias,
    void* __restrict__ C0, void* __restrict__ C1, void* __restrict__ C2,
    int ldc, int K, int nColBlk)
{
  extern __shared__ u16 lds[];   // 65536 u16 = 128 KB
  const int tid  = threadIdx.x;
  const int lane = tid & 63;
  const int w    = tid >> 6;
  const int wr   = w >> 2;       // 0..1
  const int wc   = w & 3;        // 0..3

  // XCD-contiguous swizzle: bid%8 -> XCD, 16 row-panels per XCD, row-major within band
  const int bid   = blockIdx.x;
  const int xcd   = bid & 7;
  const int local = bid >> 3;
  const int rowL  = local / nColBlk;
  const int colB  = local - rowL * nColBlk;
  const size_t rowBase = (size_t)(xcd * 16 + rowL) * 256;
  const size_t colBase = (size_t)colB * 256;

  f32x16 acc[4][2];
#pragma unroll
  for (int i = 0; i < 4; ++i)
#pragma unroll
    for (int j = 0; j < 2; ++j)
#pragma unroll
      for (int e = 0; e < 16; ++e) acc[i][j][e] = 0.f;

  const int NT = K >> 6;
  const int la32 = lane & 31;
  const int g2   = lane >> 5;
  const int f    = (la32 & 3) ^ ((la32 >> 2) & 3);
  const int puA  = ((g2 ^ f) << 3);   // u16 units; kk=1 -> ^16

  // stage one half-tile (2 gload16/thread), linear LDS dest + inverse-swizzled global source.
  // t >= NT clamps to 0 (dummy stage, keeps vmcnt queue arithmetic exact in the tail).
  auto stageA = [&](int buf, int ks, int t) {
    if (t >= NT) t = 0;
    const int kb = t * 64;
    const u16* Ab; int kc;
    if (kb < kSplit) { Ab = A0; kc = kb; } else { Ab = A1; kc = kb - kSplit; }
    u16* dst = lds + buf * 32768 + ks * 8192;
#pragma unroll
    for (int i2 = 0; i2 < 2; ++i2) {
      const int l = i2 * 512 + tid, r = l >> 2, p = l & 3;
      const int lu = p ^ (r & 3) ^ ((r >> 2) & 3);
      gload16(Ab + (rowBase + r) * (size_t)lda + kc + ks * 32 + lu * 8, dst + l * 8);
    }
  };
  auto stageB = [&](int buf, int ks, int t) {
    if (t >= NT) t = 0;
    const int kb = t * 64;
    u16* dst = lds + buf * 32768 + 16384 + ks * 8192;
#pragma unroll
    for (int i2 = 0; i2 < 2; ++i2) {
      const int l = i2 * 512 + tid, r = l >> 2, p = l & 3;
      const int lu = p ^ (r & 3) ^ ((r >> 2) & 3);
      gload16(Bw + (colBase + r) * (size_t)ldb + kb + ks * 32 + lu * 8, dst + l * 8);
    }
  };

  // LDS half-tile bases
  const u16* sA_b0k0 = lds;
  const u16* sA_b0k1 = lds + 8192;
  const u16* sB_b0k0 = lds + 16384;
  const u16* sB_b0k1 = lds + 16384 + 8192;
  const u16* sA_b1k0 = lds + 32768;
  const u16* sA_b1k1 = lds + 32768 + 8192;
  const u16* sB_b1k0 = lds + 32768 + 16384;
  const u16* sB_b1k1 = lds + 32768 + 16384 + 8192;
  const int rA0 = wr * 128;        // QM0 A rows
  const int rA1 = wr * 128 + 64;   // QM1 A rows
  const int rB  = wc * 64;

  // prologue: tile0 complete + tile1 k0-halves  (12 loads in flight)
  stageA(0, 0, 0); stageB(0, 0, 0); stageA(0, 1, 0); stageB(0, 1, 0);
  stageA(1, 0, 1); stageB(1, 0, 1);
  VM4();   // tile0 resident; tile1.k0 may fly
  SB(); BAR(); SB();

  bf16x8 a0[2][2], a1[2][2], bbE[2][2], bbO[2][2];
  const int NIT = NT >> 1;
  for (int i = 0; i < NIT; ++i) {
    const int u = 2 * i, v = 2 * i + 1;
    // ph0 (b0k0,QM0): self a0,bbE + pre a1 (same half-tile)
    readF(a0,  sA_b0k0, rA0, la32, puA);
    readF(bbE, sB_b0k0, rB,  la32, puA);
    readF(a1,  sA_b0k0, rA1, la32, puA);
    stageA(1, 1, v);
    SB(); BAR(); SB();
    PRIO1(); mfma8(acc, a0, bbE, 0); PRIO0(); SB();
    BAR(); SB();
    // ph1 (b0k0,QM1): pre a0,bbO <- b0k1
    readF(a0,  sA_b0k1, rA0, la32, puA);
    readF(bbO, sB_b0k1, rB,  la32, puA);
    stageB(1, 1, v);
    SB(); BAR(); SB();
    PRIO1(); mfma8(acc, a1, bbE, 1); PRIO0(); SB();
    BAR(); SB();
    // ph2 (b0k1,QM0): pre a1 <- b0k1
    readF(a1,  sA_b0k1, rA1, la32, puA);
    stageA(0, 0, u + 2);
    SB(); BAR(); SB();
    PRIO1(); mfma8(acc, a0, bbO, 0); PRIO0(); SB();
    VM6();   // drains prev ph6/ph7 stages -> b1k0 resident (barrier follows: cross-wave safe)
    BAR(); SB();
    // ph3 (b0k1,QM1): pre a0,bbE <- b1k0
    readF(a0,  sA_b1k0, rA0, la32, puA);
    readF(bbE, sB_b1k0, rB,  la32, puA);
    stageB(0, 0, u + 2);
    SB(); BAR(); SB();
    PRIO1(); mfma8(acc, a1, bbO, 1); PRIO0(); SB();
    VM4();   // drains ph0/ph1 stages -> b1k1 resident
    BAR(); SB();
    // ph4 (b1k0,QM0): pre a1 <- b1k0
    readF(a1,  sA_b1k0, rA1, la32, puA);
    stageA(0, 1, u + 2);
    SB(); BAR(); SB();
    PRIO1(); mfma8(acc, a0, bbE, 0); PRIO0(); SB();
    BAR(); SB();
    // ph5 (b1k0,QM1): pre a0,bbO <- b1k1
    readF(a0,  sA_b1k1, rA0, la32, puA);
    readF(bbO, sB_b1k1, rB,  la32, puA);
    stageB(0, 1, u + 2);
    SB(); BAR(); SB();
    PRIO1(); mfma8(acc, a1, bbE, 1); PRIO0(); SB();
    BAR(); SB();
    // ph6 (b1k1,QM0): pre a1 <- b1k1
    readF(a1,  sA_b1k1, rA1, la32, puA);
    stageA(1, 0, v + 2);
    SB(); BAR(); SB();
    PRIO1(); mfma8(acc, a0, bbO, 0); PRIO0(); SB();
    BAR(); SB();
    // ph7 (b1k1,QM1): no reads (next ph0's region only guaranteed by this phase's vmcnt)
    stageB(1, 0, v + 2);
    SB(); BAR(); SB();
    PRIO1(); mfma8(acc, a1, bbO, 1); PRIO0(); SB();
    VM4();   // drains ph2..ph5 stages -> buf0 tile u+2 complete
    BAR(); SB();
  }

  // epilogue: segment-select output buffer (colBase multiple of 256 -> block-uniform segment)
  const int seg = (int)(colBase >> 10);
  const size_t colSeg = colBase & 1023;
  void* Cout;
  if (EPI == 3)      Cout = (seg == 0) ? C0 : (seg == 1) ? C1 : C2;
  else if (EPI == 2) Cout = (seg == 0) ? C0 : C1;
  else               Cout = C0;

  // C/D layout (32x32x16, m74/m101): col = lane&31, row = (r&3) + 8*(r>>2) + 4*(lane>>5)
#pragma unroll
  for (int mi = 0; mi < 4; ++mi)
#pragma unroll
    for (int ni = 0; ni < 2; ++ni) {
      const int cn = wc * 64 + ni * 32 + la32;
      const float badd = (EPI == 1) ? bias[colBase + cn] : 0.0f;
      const size_t col = colSeg + cn;
#pragma unroll
      for (int r = 0; r < 16; ++r) {
        const size_t row = rowBase + wr * 128 + mi * 32 + (r & 3) + 8 * (r >> 2) + 4 * g2;
        const float v = acc[mi][ni][r] + badd;
        if (EPI == 2) ((float*)Cout)[row * (size_t)ldc + col] = v;
        else          ((u16*)Cout)[row * (size_t)ldc + col] = f2bf(v);
      }
    }
}

// ---------------- LayerNorm (in-place on bf16 rows) ----------------

__global__ __launch_bounds__(256) void ln_kernel(u16* __restrict__ xc,
    const float* __restrict__ gamma, const float* __restrict__ beta)
{
  const size_t row = blockIdx.x;
  u16* p = xc + row * D_DIM;
  const int tid = threadIdx.x;
  const int c = tid * 4;
  const uint2 raw = *(const uint2*)(p + c);
  const float v0 = bf2f((u16)(raw.x & 0xffff)), v1 = bf2f((u16)(raw.x >> 16));
  const float v2 = bf2f((u16)(raw.y & 0xffff)), v3 = bf2f((u16)(raw.y >> 16));
  float s = v0 + v1 + v2 + v3;
  float q = v0 * v0 + v1 * v1 + v2 * v2 + v3 * v3;
#pragma unroll
  for (int o = 32; o > 0; o >>= 1) { s += __shfl_xor(s, o); q += __shfl_xor(q, o); }
  __shared__ float red[8];
  if ((tid & 63) == 0) { red[(tid >> 6) * 2] = s; red[(tid >> 6) * 2 + 1] = q; }
  __syncthreads();
  s = red[0] + red[2] + red[4] + red[6];
  q = red[1] + red[3] + red[5] + red[7];
  const float mu = s * (1.0f / D_DIM);
  const float var = q * (1.0f / D_DIM) - mu * mu;
  const float rstd = 1.0f / sqrtf(var + 1e-5f);
  const float y0 = (v0 - mu) * rstd * gamma[c] + beta[c];
  const float y1 = (v1 - mu) * rstd * gamma[c + 1] + beta[c + 1];
  const float y2 = (v2 - mu) * rstd * gamma[c + 2] + beta[c + 2];
  const float y3 = (v3 - mu) * rstd * gamma[c + 3] + beta[c + 3];
  const uint32_t o0 = (uint32_t)f2bf(y0) | ((uint32_t)f2bf(y1) << 16);
  const uint32_t o1 = (uint32_t)f2bf(y2) | ((uint32_t)f2bf(y3) << 16);
  *(uint2*)(p + c) = make_uint2(o0, o1);
}

// ---------------- gate[row,h] = sigmoid(q.k / sqrt(DH)) — one wave per (row,h) ----------------

__global__ __launch_bounds__(256) void gate_kernel(
    const u16* __restrict__ Q, const u16* __restrict__ Kb, float* __restrict__ gate)
{
  const int gw = blockIdx.x * 4 + (threadIdx.x >> 6);   // wave id: row*8 + h
  const int lane = threadIdx.x & 63;
  const size_t row = (size_t)(gw >> 3);
  const int h = gw & 7;
  const size_t off = row * D_DIM + h * DH_DIM + lane * 2;
  const uint32_t qr = *(const uint32_t*)(Q + off);
  const uint32_t kr = *(const uint32_t*)(Kb + off);
  float d = bf2f((u16)(qr & 0xffff)) * bf2f((u16)(kr & 0xffff))
          + bf2f((u16)(qr >> 16))    * bf2f((u16)(kr >> 16));
#pragma unroll
  for (int o = 32; o > 0; o >>= 1) d += __shfl_xor(d, o);
  if (lane == 0) {
    const float x = d * 0.08838834764831845f;  // 1/sqrt(128)
    gate[gw] = 1.0f / (1.0f + expf(-x));
  }
}

// ---------------- sequential EMA scan over T (parallel over B*D) ----------------

__global__ __launch_bounds__(256) void scan_kernel(
    const u16* __restrict__ vb, const float* __restrict__ gate,
    const float* __restrict__ vstate, const float* __restrict__ log_alpha,
    u16* __restrict__ ret, float* __restrict__ fstate)
{
  const int gid = blockIdx.x * 256 + threadIdx.x;   // b*1024 + h*128 + d
  const int b = gid >> 10;
  const int c = gid & 1023;
  const int h = c >> 7;
  const float alpha = 1.0f / (1.0f + expf(-log_alpha[h]));
  const float oma = 1.0f - alpha;
  float state = vstate[gid];
  const u16* vp = vb + (size_t)b * D_DIM + c;
  u16* rp = ret + (size_t)b * D_DIM + c;
  const float* gp = gate + b * H_DIM + h;
#pragma unroll 4
  for (int t = 0; t < T_DIM; ++t) {
    const float v = bf2f(vp[(size_t)t * (B_DIM * D_DIM)]);
    const float g = gp[(size_t)t * (B_DIM * H_DIM)];
    state = alpha * v + oma * state;
    rp[(size_t)t * (B_DIM * D_DIM)] = f2bf(g * state);
  }
  fstate[gid] = state;
}

// ---------------- launch ----------------

extern "C" void kernel_launch(void* const* d_in, const int* in_sizes, int n_in,
                              void* d_out, int out_size, void* d_ws, size_t ws_size,
                              hipStream_t stream) {
  const float* x_real      = (const float*)d_in[0];
  const float* x_imag      = (const float*)d_in[1];
  const float* value_state = (const float*)d_in[2];
  // d_in[3] = t (unused by the math)
  const float* Wr_in  = (const float*)d_in[4];
  const float* Wi_in  = (const float*)d_in[5];
  const float* br_in  = (const float*)d_in[6];
  const float* bi_in  = (const float*)d_in[7];
  const float* ln_g   = (const float*)d_in[8];
  const float* ln_b   = (const float*)d_in[9];
  const float* W_qkv  = (const float*)d_in[10];
  const float* log_alpha = (const float*)d_in[11];
  const float* Wr_out = (const float*)d_in[12];
  const float* Wi_out = (const float*)d_in[13];

  float* out_real = (float*)d_out;
  float* out_imag = out_real + (size_t)MROWS * D_DIM;
  float* fstate   = out_imag + (size_t)MROWS * D_DIM;

  // Scratch carved out of d_out (regions dead until the final out-proj GEMM):
  u16* R0a = (u16*)d_out;                                        // xr -> Q -> (dead)
  u16* xc  = (u16*)((char*)d_out + (size_t)MROWS * D_DIM * 2);   // proj out, LN'd
  u16* Vb  = (u16*)out_imag;                                     // V

  // d_ws buffers (~79 MB)
  char* ws = (char*)d_ws;
  size_t off = 0;
  auto alloc = [&](size_t bytes) { void* p = ws + off; off += (bytes + 255) & ~(size_t)255; return p; };
  u16*   Wc    = (u16*)alloc((size_t)1024 * 2048 * 2);
  u16*   Wqkvb = (u16*)alloc((size_t)3072 * 1024 * 2);
  u16*   Wob   = (u16*)alloc((size_t)2048 * 1024 * 2);   // [Wr_out; Wi_out]
  float* bc    = (float*)alloc((size_t)D_DIM * 4);
  u16*   R0b   = (u16*)alloc((size_t)MROWS * D_DIM * 2); // xi -> K -> retrieved
  float* gate  = (float*)alloc((size_t)MROWS * H_DIM * 4);

  // allow 128 KB dynamic LDS for the GEMM instantiations (host-side, capture-safe)
  const int LDSB = 131072;
  hipFuncSetAttribute((const void*)gemm256_kernel<1>, hipFuncAttributeMaxDynamicSharedMemorySize, LDSB);
  hipFuncSetAttribute((const void*)gemm256_kernel<2>, hipFuncAttributeMaxDynamicSharedMemorySize, LDSB);
  hipFuncSetAttribute((const void*)gemm256_kernel<3>, hipFuncAttributeMaxDynamicSharedMemorySize, LDSB);

  // --- weight prep ---
  prep_wc_kernel<<<(1024 * 2048) / 256, 256, 0, stream>>>(Wr_in, Wi_in, Wc);
  prep_bc_kernel<<<4, 256, 0, stream>>>(br_in, bi_in, bc);
  cast_bf16_kernel<<<1536, 256, 0, stream>>>(W_qkv, Wqkvb, (size_t)3072 * 1024 / 8);
  cast_bf16_kernel<<<512, 256, 0, stream>>>(Wr_out, Wob, (size_t)1024 * 1024 / 8);
  cast_bf16_kernel<<<512, 256, 0, stream>>>(Wi_out, Wob + (size_t)1024 * 1024, (size_t)1024 * 1024 / 8);
  // --- activation casts ---
  cast_bf16_kernel<<<4096, 256, 0, stream>>>(x_real, R0a, (size_t)MROWS * D_DIM / 8);
  cast_bf16_kernel<<<4096, 256, 0, stream>>>(x_imag, R0b, (size_t)MROWS * D_DIM / 8);

  // input proj: xc_pre = [xr|xi] @ Wc^T + bc   (K=2048, split at 1024) -> xc
  gemm256_kernel<1><<<dim3(128 * 4), 512, LDSB, stream>>>(
      R0a, R0b, 1024, 1024, Wc, 2048, bc, xc, nullptr, nullptr, 1024, 2048, 4);
  // LayerNorm in place
  ln_kernel<<<MROWS, 256, 0, stream>>>(xc, ln_g, ln_b);
  // QKV in ONE GEMM (N=3072): Q -> R0a, K -> R0b, V -> Vb
  gemm256_kernel<3><<<dim3(128 * 12), 512, LDSB, stream>>>(
      xc, xc, 1024, 1024, Wqkvb, 1024, nullptr, R0a, R0b, Vb, 1024, 1024, 12);
  // gate from Q,K
  gate_kernel<<<(MROWS * H_DIM) / 4, 256, 0, stream>>>(R0a, R0b, gate);
  // EMA scan: retrieved -> R0b (overwrites dead K), final_state -> d_out tail
  scan_kernel<<<(B_DIM * D_DIM) / 256, 256, 0, stream>>>(Vb, gate, value_state, log_alpha, R0b, fstate);
  // output projections in ONE GEMM (N=2048, f32 out): -> out_real | out_imag
  gemm256_kernel<2><<<dim3(128 * 8), 512, LDSB, stream>>>(
      R0b, R0b, 1024, 1024, Wob, 1024, nullptr, out_real, out_imag, nullptr, 1024, 1024, 8);
}

// Round 9
// 706.287 us; speedup vs baseline: 1.0666x; 1.0630x over previous
//
#include <hip/hip_runtime.h>
#include <stdint.h>

#define T_DIM 512
#define B_DIM 64
#define D_DIM 1024
#define H_DIM 8
#define DH_DIM 128
#define MROWS (T_DIM * B_DIM)   // 32768 rows across all timesteps

typedef unsigned short u16;
typedef __attribute__((ext_vector_type(8))) __bf16 bf16x8;
typedef __attribute__((ext_vector_type(4))) float f32x4;
typedef __attribute__((ext_vector_type(16))) float f32x16;

__device__ __forceinline__ u16 f2bf(float f) {
  union { float f; uint32_t u; } v; v.f = f;
  uint32_t u = v.u;
  u += 0x7fffu + ((u >> 16) & 1u);   // RNE
  return (u16)(u >> 16);
}
__device__ __forceinline__ float bf2f(u16 h) {
  union { uint32_t u; float f; } v; v.u = ((uint32_t)h) << 16;
  return v.f;
}

__device__ __forceinline__ void gload16(const void* g, void* l) {
  __builtin_amdgcn_global_load_lds(
      (const __attribute__((address_space(1))) uint32_t*)g,
      (__attribute__((address_space(3))) uint32_t*)l, 16, 0, 0);
}

#define SB()  __builtin_amdgcn_sched_barrier(0)
#define BAR() __builtin_amdgcn_s_barrier()
#define VM4() asm volatile("s_waitcnt vmcnt(4)" ::: "memory")
#define VM6() asm volatile("s_waitcnt vmcnt(6)" ::: "memory")
#define PRIO1() __builtin_amdgcn_s_setprio(1)
#define PRIO0() __builtin_amdgcn_s_setprio(0)

// ---------------- merged elementwise prep ----------------

__device__ __forceinline__ void cast8(const float* __restrict__ in, u16* __restrict__ out, size_t i) {
  const float4 a = ((const float4*)in)[i * 2];
  const float4 b = ((const float4*)in)[i * 2 + 1];
  union { u16 h[8]; uint4 u; } o;
  o.h[0] = f2bf(a.x); o.h[1] = f2bf(a.y); o.h[2] = f2bf(a.z); o.h[3] = f2bf(a.w);
  o.h[4] = f2bf(b.x); o.h[5] = f2bf(b.y); o.h[6] = f2bf(b.z); o.h[7] = f2bf(b.w);
  ((uint4*)out)[i] = o.u;
}

// One launch: Wc combine (8192 blks) | Wqkv cast (1536) | Wr_out cast (512) | Wi_out cast (512) | bc (4)
__global__ void prep_all_kernel(const float* __restrict__ Wr, const float* __restrict__ Wi,
                                const float* __restrict__ br, const float* __restrict__ bi,
                                const float* __restrict__ Wqkv,
                                const float* __restrict__ Wro, const float* __restrict__ Wio,
                                u16* __restrict__ Wc, float* __restrict__ bc,
                                u16* __restrict__ Wqkvb, u16* __restrict__ Wob) {
  const int blk = blockIdx.x;
  if (blk < 8192) {                      // Wc[n][k]: (1024,2048) bf16
    const int idx = blk * 256 + threadIdx.x;
    const int n = idx >> 11;
    const int k = idx & 2047;
    const int kk = k & 1023;
    const float a = Wr[n * 1024 + kk], b = Wi[n * 1024 + kk];
    Wc[idx] = f2bf(k < 1024 ? a + b : a - b);
  } else if (blk < 9728) {               // W_qkv cast: 393216 8-elem units
    cast8(Wqkv, Wqkvb, (size_t)(blk - 8192) * 256 + threadIdx.x);
  } else if (blk < 10240) {              // Wr_out -> Wob[0:]
    cast8(Wro, Wob, (size_t)(blk - 9728) * 256 + threadIdx.x);
  } else if (blk < 10752) {              // Wi_out -> Wob[1024*1024:]
    cast8(Wio, Wob + (size_t)1024 * 1024, (size_t)(blk - 10240) * 256 + threadIdx.x);
  } else {                               // bc
    const int i = (blk - 10752) * 256 + threadIdx.x;
    if (i < D_DIM) bc[i] = br[i] + bi[i];
  }
}

// Both activation casts in one launch: blocks [0,4096) x_real, [4096,8192) x_imag; 4 units/thread
__global__ void cast2_kernel(const float* __restrict__ xr, const float* __restrict__ xi,
                             u16* __restrict__ outr, u16* __restrict__ outi) {
  int blk = blockIdx.x;
  const float* src; u16* dst;
  if (blk < 4096) { src = xr; dst = outr; } else { src = xi; dst = outi; blk -= 4096; }
  const size_t base = (size_t)blk * 1024 + threadIdx.x;
#pragma unroll
  for (int q = 0; q < 4; ++q) cast8(src, dst, base + q * 256);
}

// ------- 256x256 8-phase bf16 MFMA GEMM (32x32x16), one-phase-ahead register pipeline -------
// (unchanged from round 8 — race-proven: absmax bit-exact, 0 bank conflicts)
// 512 threads = 8 waves (2M x 4N), per-wave C 128x64 = 4x2 frags of 32x32, BK=64, 2 K-tiles/iter.
// LDS 128 KB: [buf:2][ Ak0 | Ak1 | Bk0 | Bk1 ], half-tile 8192 u16 ([row][4 punits][8]).
// Swizzle: punit stored = u ^ (r&3) ^ ((r>>2)&3) via inverse-swizzled GLOBAL source; read punit
// lane-constant. Counted vmcnt before barriers only; tail stages CLAMP t to 0 (queue exactness).

__device__ __forceinline__ void readF(bf16x8 (&d)[2][2], const u16* s, int rowoff, int la32, int puA) {
#pragma unroll
  for (int mf = 0; mf < 2; ++mf)
#pragma unroll
    for (int kk = 0; kk < 2; ++kk)
      d[mf][kk] = *(const bf16x8*)(s + (rowoff + mf * 32 + la32) * 32 + (puA ^ (kk << 4)));
}

__device__ __forceinline__ void mfma8(f32x16 (&acc)[4][2], const bf16x8 (&a)[2][2],
                                      const bf16x8 (&b)[2][2], int QM) {
#pragma unroll
  for (int kk = 0; kk < 2; ++kk)
#pragma unroll
    for (int mf = 0; mf < 2; ++mf)
#pragma unroll
      for (int nf = 0; nf < 2; ++nf)
        acc[QM * 2 + mf][nf] =
            __builtin_amdgcn_mfma_f32_32x32x16_bf16(a[mf][kk], b[nf][kk], acc[QM * 2 + mf][nf], 0, 0, 0);
}

template <int EPI>
__global__ __launch_bounds__(512, 2) void gemm256_kernel(
    const u16* __restrict__ A0, const u16* __restrict__ A1, int kSplit, int lda,
    const u16* __restrict__ Bw, int ldb,
    const float* __restrict__ bias,
    void* __restrict__ C0, void* __restrict__ C1, void* __restrict__ C2,
    int ldc, int K, int nColBlk)
{
  extern __shared__ u16 lds[];   // 65536 u16 = 128 KB
  const int tid  = threadIdx.x;
  const int lane = tid & 63;
  const int w    = tid >> 6;
  const int wr   = w >> 2;       // 0..1
  const int wc   = w & 3;        // 0..3

  const int bid   = blockIdx.x;
  const int xcd   = bid & 7;
  const int local = bid >> 3;
  const int rowL  = local / nColBlk;
  const int colB  = local - rowL * nColBlk;
  const size_t rowBase = (size_t)(xcd * 16 + rowL) * 256;
  const size_t colBase = (size_t)colB * 256;

  f32x16 acc[4][2];
#pragma unroll
  for (int i = 0; i < 4; ++i)
#pragma unroll
    for (int j = 0; j < 2; ++j)
#pragma unroll
      for (int e = 0; e < 16; ++e) acc[i][j][e] = 0.f;

  const int NT = K >> 6;
  const int la32 = lane & 31;
  const int g2   = lane >> 5;
  const int f    = (la32 & 3) ^ ((la32 >> 2) & 3);
  const int puA  = ((g2 ^ f) << 3);   // u16 units; kk=1 -> ^16

  auto stageA = [&](int buf, int ks, int t) {
    if (t >= NT) t = 0;   // dummy stage keeps vmcnt queue exact in the tail
    const int kb = t * 64;
    const u16* Ab; int kc;
    if (kb < kSplit) { Ab = A0; kc = kb; } else { Ab = A1; kc = kb - kSplit; }
    u16* dst = lds + buf * 32768 + ks * 8192;
#pragma unroll
    for (int i2 = 0; i2 < 2; ++i2) {
      const int l = i2 * 512 + tid, r = l >> 2, p = l & 3;
      const int lu = p ^ (r & 3) ^ ((r >> 2) & 3);
      gload16(Ab + (rowBase + r) * (size_t)lda + kc + ks * 32 + lu * 8, dst + l * 8);
    }
  };
  auto stageB = [&](int buf, int ks, int t) {
    if (t >= NT) t = 0;
    const int kb = t * 64;
    u16* dst = lds + buf * 32768 + 16384 + ks * 8192;
#pragma unroll
    for (int i2 = 0; i2 < 2; ++i2) {
      const int l = i2 * 512 + tid, r = l >> 2, p = l & 3;
      const int lu = p ^ (r & 3) ^ ((r >> 2) & 3);
      gload16(Bw + (colBase + r) * (size_t)ldb + kb + ks * 32 + lu * 8, dst + l * 8);
    }
  };

  const u16* sA_b0k0 = lds;
  const u16* sA_b0k1 = lds + 8192;
  const u16* sB_b0k0 = lds + 16384;
  const u16* sB_b0k1 = lds + 16384 + 8192;
  const u16* sA_b1k0 = lds + 32768;
  const u16* sA_b1k1 = lds + 32768 + 8192;
  const u16* sB_b1k0 = lds + 32768 + 16384;
  const u16* sB_b1k1 = lds + 32768 + 16384 + 8192;
  const int rA0 = wr * 128;
  const int rA1 = wr * 128 + 64;
  const int rB  = wc * 64;

  stageA(0, 0, 0); stageB(0, 0, 0); stageA(0, 1, 0); stageB(0, 1, 0);
  stageA(1, 0, 1); stageB(1, 0, 1);
  VM4();
  SB(); BAR(); SB();

  bf16x8 a0[2][2], a1[2][2], bbE[2][2], bbO[2][2];
  const int NIT = NT >> 1;
  for (int i = 0; i < NIT; ++i) {
    const int u = 2 * i, v = 2 * i + 1;
    readF(a0,  sA_b0k0, rA0, la32, puA);
    readF(bbE, sB_b0k0, rB,  la32, puA);
    readF(a1,  sA_b0k0, rA1, la32, puA);
    stageA(1, 1, v);
    SB(); BAR(); SB();
    PRIO1(); mfma8(acc, a0, bbE, 0); PRIO0(); SB();
    BAR(); SB();
    readF(a0,  sA_b0k1, rA0, la32, puA);
    readF(bbO, sB_b0k1, rB,  la32, puA);
    stageB(1, 1, v);
    SB(); BAR(); SB();
    PRIO1(); mfma8(acc, a1, bbE, 1); PRIO0(); SB();
    BAR(); SB();
    readF(a1,  sA_b0k1, rA1, la32, puA);
    stageA(0, 0, u + 2);
    SB(); BAR(); SB();
    PRIO1(); mfma8(acc, a0, bbO, 0); PRIO0(); SB();
    VM6();
    BAR(); SB();
    readF(a0,  sA_b1k0, rA0, la32, puA);
    readF(bbE, sB_b1k0, rB,  la32, puA);
    stageB(0, 0, u + 2);
    SB(); BAR(); SB();
    PRIO1(); mfma8(acc, a1, bbO, 1); PRIO0(); SB();
    VM4();
    BAR(); SB();
    readF(a1,  sA_b1k0, rA1, la32, puA);
    stageA(0, 1, u + 2);
    SB(); BAR(); SB();
    PRIO1(); mfma8(acc, a0, bbE, 0); PRIO0(); SB();
    BAR(); SB();
    readF(a0,  sA_b1k1, rA0, la32, puA);
    readF(bbO, sB_b1k1, rB,  la32, puA);
    stageB(0, 1, u + 2);
    SB(); BAR(); SB();
    PRIO1(); mfma8(acc, a1, bbE, 1); PRIO0(); SB();
    BAR(); SB();
    readF(a1,  sA_b1k1, rA1, la32, puA);
    stageA(1, 0, v + 2);
    SB(); BAR(); SB();
    PRIO1(); mfma8(acc, a0, bbO, 0); PRIO0(); SB();
    BAR(); SB();
    stageB(1, 0, v + 2);
    SB(); BAR(); SB();
    PRIO1(); mfma8(acc, a1, bbO, 1); PRIO0(); SB();
    VM4();
    BAR(); SB();
  }

  const int seg = (int)(colBase >> 10);
  const size_t colSeg = colBase & 1023;
  void* Cout;
  if (EPI == 3)      Cout = (seg == 0) ? C0 : (seg == 1) ? C1 : C2;
  else if (EPI == 2) Cout = (seg == 0) ? C0 : C1;
  else               Cout = C0;

  // C/D layout (32x32x16, m74/m101): col = lane&31, row = (r&3) + 8*(r>>2) + 4*(lane>>5)
#pragma unroll
  for (int mi = 0; mi < 4; ++mi)
#pragma unroll
    for (int ni = 0; ni < 2; ++ni) {
      const int cn = wc * 64 + ni * 32 + la32;
      const float badd = (EPI == 1) ? bias[colBase + cn] : 0.0f;
      const size_t col = colSeg + cn;
#pragma unroll
      for (int r = 0; r < 16; ++r) {
        const size_t row = rowBase + wr * 128 + mi * 32 + (r & 3) + 8 * (r >> 2) + 4 * g2;
        const float v = acc[mi][ni][r] + badd;
        if (EPI == 2) ((float*)Cout)[row * (size_t)ldc + col] = v;
        else          ((u16*)Cout)[row * (size_t)ldc + col] = f2bf(v);
      }
    }
}

// ---------------- LayerNorm (in-place on bf16 rows) ----------------

__global__ __launch_bounds__(256) void ln_kernel(u16* __restrict__ xc,
    const float* __restrict__ gamma, const float* __restrict__ beta)
{
  const size_t row = blockIdx.x;
  u16* p = xc + row * D_DIM;
  const int tid = threadIdx.x;
  const int c = tid * 4;
  const uint2 raw = *(const uint2*)(p + c);
  const float v0 = bf2f((u16)(raw.x & 0xffff)), v1 = bf2f((u16)(raw.x >> 16));
  const float v2 = bf2f((u16)(raw.y & 0xffff)), v3 = bf2f((u16)(raw.y >> 16));
  float s = v0 + v1 + v2 + v3;
  float q = v0 * v0 + v1 * v1 + v2 * v2 + v3 * v3;
#pragma unroll
  for (int o = 32; o > 0; o >>= 1) { s += __shfl_xor(s, o); q += __shfl_xor(q, o); }
  __shared__ float red[8];
  if ((tid & 63) == 0) { red[(tid >> 6) * 2] = s; red[(tid >> 6) * 2 + 1] = q; }
  __syncthreads();
  s = red[0] + red[2] + red[4] + red[6];
  q = red[1] + red[3] + red[5] + red[7];
  const float mu = s * (1.0f / D_DIM);
  const float var = q * (1.0f / D_DIM) - mu * mu;
  const float rstd = 1.0f / sqrtf(var + 1e-5f);
  const float y0 = (v0 - mu) * rstd * gamma[c] + beta[c];
  const float y1 = (v1 - mu) * rstd * gamma[c + 1] + beta[c + 1];
  const float y2 = (v2 - mu) * rstd * gamma[c + 2] + beta[c + 2];
  const float y3 = (v3 - mu) * rstd * gamma[c + 3] + beta[c + 3];
  const uint32_t o0 = (uint32_t)f2bf(y0) | ((uint32_t)f2bf(y1) << 16);
  const uint32_t o1 = (uint32_t)f2bf(y2) | ((uint32_t)f2bf(y3) << 16);
  *(uint2*)(p + c) = make_uint2(o0, o1);
}

// ---------------- gate[row,h] = sigmoid(q.k / sqrt(DH)) — one wave per (row,h) ----------------

__global__ __launch_bounds__(256) void gate_kernel(
    const u16* __restrict__ Q, const u16* __restrict__ Kb, float* __restrict__ gate)
{
  const int gw = blockIdx.x * 4 + (threadIdx.x >> 6);   // wave id: row*8 + h
  const int lane = threadIdx.x & 63;
  const size_t row = (size_t)(gw >> 3);
  const int h = gw & 7;
  const size_t off = row * D_DIM + h * DH_DIM + lane * 2;
  const uint32_t qr = *(const uint32_t*)(Q + off);
  const uint32_t kr = *(const uint32_t*)(Kb + off);
  float d = bf2f((u16)(qr & 0xffff)) * bf2f((u16)(kr & 0xffff))
          + bf2f((u16)(qr >> 16))    * bf2f((u16)(kr >> 16));
#pragma unroll
  for (int o = 32; o > 0; o >>= 1) d += __shfl_xor(d, o);
  if (lane == 0) {
    const float x = d * 0.08838834764831845f;  // 1/sqrt(128)
    gate[gw] = 1.0f / (1.0f + expf(-x));
  }
}

// ---------------- chunked EMA scan: 8 chunks of 64 timesteps ----------------
// state_t = a*v_t + (1-a)*state_{t-1} is a linear recurrence; chunk-decompose:
//   phase 1: L_j = chunk-local end state with zero carry  (exact algebra)
//   phase 2: carry_j = fold_{i<j}(L_i, oma^64) from vstate; replay chunk with true carry.
// 8x parallelism vs the 512-step serial scan (16 waves/CU), 2 d's per thread.

__global__ __launch_bounds__(256) void scan1_kernel(
    const u16* __restrict__ vb, const float* __restrict__ log_alpha,
    float* __restrict__ carry)          // carry[8][B*D]
{
  const int j  = blockIdx.x >> 7;                         // chunk 0..7
  const int th = (blockIdx.x & 127) * 256 + threadIdx.x;  // 0..32767
  const int gid = th * 2;                                 // b*1024 + c (even)
  const int b = gid >> 10;
  const int c = gid & 1023;
  const int h = c >> 7;
  const float alpha = 1.0f / (1.0f + expf(-log_alpha[h]));
  const float oma = 1.0f - alpha;
  const u16* vp = vb + ((size_t)(4096 * j + b)) * 1024 + c;   // row = (64j+i)*64 + b
  float s0 = 0.f, s1 = 0.f;
#pragma unroll 8
  for (int i = 0; i < 64; ++i) {
    const uint32_t uv = *(const uint32_t*)(vp + (size_t)i * 65536);
    s0 = alpha * bf2f((u16)(uv & 0xffff)) + oma * s0;
    s1 = alpha * bf2f((u16)(uv >> 16))    + oma * s1;
  }
  *(float2*)(carry + (size_t)j * 65536 + gid) = make_float2(s0, s1);
}

__global__ __launch_bounds__(256) void scan2_kernel(
    const u16* __restrict__ vb, const float* __restrict__ gate,
    const float* __restrict__ vstate, const float* __restrict__ log_alpha,
    const float* __restrict__ carry,
    u16* __restrict__ ret, float* __restrict__ fstate)
{
  const int j  = blockIdx.x >> 7;
  const int th = (blockIdx.x & 127) * 256 + threadIdx.x;
  const int gid = th * 2;
  const int b = gid >> 10;
  const int c = gid & 1023;
  const int h = c >> 7;
  const float alpha = 1.0f / (1.0f + expf(-log_alpha[h]));
  const float oma = 1.0f - alpha;
  float o64 = oma;
#pragma unroll
  for (int q = 0; q < 6; ++q) o64 *= o64;   // oma^64
  float s0 = vstate[gid], s1 = vstate[gid + 1];
  for (int i = 0; i < j; ++i) {             // carry_j = L_{j-1} + o64*carry_{j-1}
    const float2 L = *(const float2*)(carry + (size_t)i * 65536 + gid);
    s0 = L.x + o64 * s0;
    s1 = L.y + o64 * s1;
  }
  const u16* vp = vb + ((size_t)(4096 * j + b)) * 1024 + c;
  u16* rp = ret + ((size_t)(4096 * j + b)) * 1024 + c;
  const float* gp = gate + (size_t)(4096 * j + b) * H_DIM + h;
#pragma unroll 4
  for (int i = 0; i < 64; ++i) {
    const uint32_t uv = *(const uint32_t*)(vp + (size_t)i * 65536);
    const float g = gp[(size_t)i * 512];
    s0 = alpha * bf2f((u16)(uv & 0xffff)) + oma * s0;
    s1 = alpha * bf2f((u16)(uv >> 16))    + oma * s1;
    const uint32_t o = (uint32_t)f2bf(g * s0) | ((uint32_t)f2bf(g * s1) << 16);
    *(uint32_t*)(rp + (size_t)i * 65536) = o;
  }
  if (j == 7) { fstate[gid] = s0; fstate[gid + 1] = s1; }
}

// ---------------- launch ----------------

extern "C" void kernel_launch(void* const* d_in, const int* in_sizes, int n_in,
                              void* d_out, int out_size, void* d_ws, size_t ws_size,
                              hipStream_t stream) {
  const float* x_real      = (const float*)d_in[0];
  const float* x_imag      = (const float*)d_in[1];
  const float* value_state = (const float*)d_in[2];
  // d_in[3] = t (unused by the math)
  const float* Wr_in  = (const float*)d_in[4];
  const float* Wi_in  = (const float*)d_in[5];
  const float* br_in  = (const float*)d_in[6];
  const float* bi_in  = (const float*)d_in[7];
  const float* ln_g   = (const float*)d_in[8];
  const float* ln_b   = (const float*)d_in[9];
  const float* W_qkv  = (const float*)d_in[10];
  const float* log_alpha = (const float*)d_in[11];
  const float* Wr_out = (const float*)d_in[12];
  const float* Wi_out = (const float*)d_in[13];

  float* out_real = (float*)d_out;
  float* out_imag = out_real + (size_t)MROWS * D_DIM;
  float* fstate   = out_imag + (size_t)MROWS * D_DIM;

  // Scratch carved out of d_out (regions dead until the final out-proj GEMM):
  u16* R0a = (u16*)d_out;                                        // xr -> Q -> (dead)
  u16* xc  = (u16*)((char*)d_out + (size_t)MROWS * D_DIM * 2);   // proj out, LN'd
  u16* Vb  = (u16*)out_imag;                                     // V

  // d_ws buffers (~81 MB)
  char* ws = (char*)d_ws;
  size_t off = 0;
  auto alloc = [&](size_t bytes) { void* p = ws + off; off += (bytes + 255) & ~(size_t)255; return p; };
  u16*   Wc    = (u16*)alloc((size_t)1024 * 2048 * 2);
  u16*   Wqkvb = (u16*)alloc((size_t)3072 * 1024 * 2);
  u16*   Wob   = (u16*)alloc((size_t)2048 * 1024 * 2);   // [Wr_out; Wi_out]
  float* bc    = (float*)alloc((size_t)D_DIM * 4);
  u16*   R0b   = (u16*)alloc((size_t)MROWS * D_DIM * 2); // xi -> K -> retrieved
  float* gate  = (float*)alloc((size_t)MROWS * H_DIM * 4);
  float* carry = (float*)alloc((size_t)8 * B_DIM * D_DIM * 4);   // 2 MB

  // allow 128 KB dynamic LDS for the GEMM instantiations (host-side, capture-safe)
  const int LDSB = 131072;
  hipFuncSetAttribute((const void*)gemm256_kernel<1>, hipFuncAttributeMaxDynamicSharedMemorySize, LDSB);
  hipFuncSetAttribute((const void*)gemm256_kernel<2>, hipFuncAttributeMaxDynamicSharedMemorySize, LDSB);
  hipFuncSetAttribute((const void*)gemm256_kernel<3>, hipFuncAttributeMaxDynamicSharedMemorySize, LDSB);

  // --- prep (one launch) + activation casts (one launch) ---
  prep_all_kernel<<<10756, 256, 0, stream>>>(Wr_in, Wi_in, br_in, bi_in, W_qkv, Wr_out, Wi_out,
                                             Wc, bc, Wqkvb, Wob);
  cast2_kernel<<<8192, 256, 0, stream>>>(x_real, x_imag, R0a, R0b);

  // input proj: xc_pre = [xr|xi] @ Wc^T + bc   (K=2048, split at 1024) -> xc
  gemm256_kernel<1><<<dim3(128 * 4), 512, LDSB, stream>>>(
      R0a, R0b, 1024, 1024, Wc, 2048, bc, xc, nullptr, nullptr, 1024, 2048, 4);
  // LayerNorm in place
  ln_kernel<<<MROWS, 256, 0, stream>>>(xc, ln_g, ln_b);
  // QKV in ONE GEMM (N=3072): Q -> R0a, K -> R0b, V -> Vb
  gemm256_kernel<3><<<dim3(128 * 12), 512, LDSB, stream>>>(
      xc, xc, 1024, 1024, Wqkvb, 1024, nullptr, R0a, R0b, Vb, 1024, 1024, 12);
  // gate from Q,K
  gate_kernel<<<(MROWS * H_DIM) / 4, 256, 0, stream>>>(R0a, R0b, gate);
  // chunked EMA scan: carries, then replay with true carry -> retrieved in R0b
  scan1_kernel<<<1024, 256, 0, stream>>>(Vb, log_alpha, carry);
  scan2_kernel<<<1024, 256, 0, stream>>>(Vb, gate, value_state, log_alpha, carry, R0b, fstate);
  // output projections in ONE GEMM (N=2048, f32 out): -> out_real | out_imag
  gemm256_kernel<2><<<dim3(128 * 8), 512, LDSB, stream>>>(
      R0b, R0b, 1024, 1024, Wob, 1024, nullptr, out_real, out_imag, nullptr, 1024, 1024, 8);
}